// Round 4
// baseline (15064.127 us; speedup 1.0000x reference)
//
#include <hip/hip_runtime.h>
#include <stdint.h>

typedef _Float16 h2 __attribute__((ext_vector_type(2)));
typedef float    f4 __attribute__((ext_vector_type(4)));
typedef uint32_t u4 __attribute__((ext_vector_type(4)));

#if __has_builtin(__builtin_amdgcn_fdot2)
__device__ __forceinline__ float dot2(uint32_t a, uint32_t b, float c) {
    return __builtin_amdgcn_fdot2(__builtin_bit_cast(h2, a),
                                  __builtin_bit_cast(h2, b), c, false);
}
#else
__device__ __forceinline__ float dot2(uint32_t a, uint32_t b, float c) {
    h2 ha = __builtin_bit_cast(h2, a), hb = __builtin_bit_cast(h2, b);
    return c + (float)ha[0]*(float)hb[0] + (float)ha[1]*(float)hb[1];
}
#endif

// tanh(z) = 1 - 2/(exp(2z)+1); v_exp_f32 + v_rcp path.
__device__ __forceinline__ float fast_tanh(float z) {
    float e = __expf(2.0f * z);
    return 1.0f - 2.0f * __builtin_amdgcn_rcpf(e + 1.0f);
}

#define TT 4096
#define NB 32
#define HD 512
#define KG 8               // k-groups: 8 x 64-row slices
#define JP 32              // half2 k-pairs per col per thread (64 rows / 2)

// One block per batch row, 1024 threads (16 waves = 4 waves/SIMD for stall
// hiding). Thread = (kg 0..7) x (colg 0..127): owns 4 output columns over a
// 64-row k-slice. W_int is ENTIRELY register-resident: 4 cols x 32 half2
// pairs = 128 words/thread (unified VGPR/AGPR file; dot2 reads AGPRs
// directly). Zero W LDS traffic per step (round 2 paid ~1150 cyc/CU/step for
// it). State distribution stays LDS-broadcast b128 (round 3 showed readlane
// serialization loses to broadcast reads). pads is an 8-way reduce.
__global__ __attribute__((amdgpu_waves_per_eu(4, 4))) __launch_bounds__(1024)
void esn_kernel(const float* __restrict__ X, const float* __restrict__ W_in,
                const float* __restrict__ W_int, const float* __restrict__ noise,
                float* __restrict__ out)
{
    __shared__ __align__(16) _Float16 s_buf[2][HD];  // 2 KB (state fp16, dbuf)
    __shared__ float pads[KG][HD];                   // 16 KB (per-kg partials)

    const int tid  = threadIdx.x;
    const int b    = blockIdx.x;
    const int kg   = tid >> 7;      // 0..7  (k-slice of 64 state rows)
    const int colg = tid & 127;     // 0..127
    const int c0   = colg * 4;      // first of this thread's 4 columns

    // Input weights for the reduce phase (col = tid, threads 0..511 only).
    float win0 = 0.f, win1 = 0.f, win2 = 0.f;
    if (tid < HD) {
        win0 = W_in[tid*3 + 0];
        win1 = W_in[tid*3 + 1];
        win2 = W_in[tid*3 + 2];
    }

    // ---- Prologue: load + pack this thread's W_int slice (fp32 -> half2) ----
    uint32_t wreg[4][JP];           // 128 words, MUST stay register-resident
    {
        const f4* Wv = (const f4*)W_int;   // W_int[k][h], 4 cols at a time
        #pragma unroll
        for (int j = 0; j < JP; ++j) {
            const int k = kg*64 + 2*j;
            f4 r0 = Wv[(size_t)k*128 + colg];
            f4 r1 = Wv[(size_t)(k+1)*128 + colg];
            #pragma unroll
            for (int c = 0; c < 4; ++c) {
                h2 hw; hw[0] = (_Float16)r0[c]; hw[1] = (_Float16)r1[c];
                wreg[c][j] = __builtin_bit_cast(uint32_t, hw);
            }
        }
    }
    if (tid < HD) s_buf[0][tid] = (_Float16)0.01f;   // prev0 = 0.01
    __syncthreads();

    const float* Xb   = X   + (size_t)b * TT * 3;
    float*       outb = out + (size_t)b * TT * HD;

    int cur = 0;
    for (int t = 0; t < TT; ++t) {
        // Prefetch this step's noise + raw input early; consumed in phase B.
        float nz = 0.f, x0 = 0.f, x1 = 0.f, x2 = 0.f;
        if (tid < HD) {
            nz = noise[((size_t)t*NB + b)*HD + tid];
            x0 = Xb[t*3 + 0];
            x1 = Xb[t*3 + 1];
            x2 = Xb[t*3 + 2];
        }

        // ---- Phase A: partial dot over this thread's 64-row k-slice ----
        // 8 broadcast b128 quads (all lanes same address -> bank-line bcast).
        const u4* sv4 = (const u4*)(&s_buf[cur][0]);
        float a0 = 0.f, a1 = 0.f, a2 = 0.f, a3 = 0.f;
        u4 sq;

        #pragma unroll
        for (int j = 0; j < JP; ++j) {
            if ((j & 3) == 0) sq = sv4[kg*8 + (j >> 2)];
            const uint32_t sv = sq[j & 3];
            a0 = dot2(sv, wreg[0][j], a0);
            a1 = dot2(sv, wreg[1][j], a1);
            a2 = dot2(sv, wreg[2][j], a2);
            a3 = dot2(sv, wreg[3][j], a3);
        }
        f4 pv; pv[0] = a0; pv[1] = a1; pv[2] = a2; pv[3] = a3;
        *(f4*)&pads[kg][c0] = pv;        // 16B aligned, conflict-free
        __syncthreads();

        // ---- Phase B: 8-way reduce, add input+noise, tanh, emit ----
        if (tid < HD) {
            float z = 0.f;
            #pragma unroll
            for (int k = 0; k < KG; ++k) z += pads[k][tid];
            z += win0*x0 + win1*x1 + win2*x2 + 0.01f*nz;
            const float s = fast_tanh(z);
            outb[(size_t)t*HD + tid] = s;
            s_buf[cur^1][tid] = (_Float16)s;
        }
        __syncthreads();
        cur ^= 1;
    }
}

extern "C" void kernel_launch(void* const* d_in, const int* in_sizes, int n_in,
                              void* d_out, int out_size, void* d_ws, size_t ws_size,
                              hipStream_t stream)
{
    const float* X     = (const float*)d_in[0];
    const float* W_in  = (const float*)d_in[1];
    const float* W_int = (const float*)d_in[2];
    const float* noise = (const float*)d_in[3];
    float* out = (float*)d_out;

    esn_kernel<<<dim3(NB), dim3(1024), 0, stream>>>(X, W_in, W_int, noise, out);
}

// Round 5
// 5376.359 us; speedup vs baseline: 2.8019x; 2.8019x over previous
//
#include <hip/hip_runtime.h>
#include <stdint.h>

typedef _Float16 h2 __attribute__((ext_vector_type(2)));
typedef float    f4 __attribute__((ext_vector_type(4)));
typedef uint32_t u4 __attribute__((ext_vector_type(4)));

#if __has_builtin(__builtin_amdgcn_fdot2)
__device__ __forceinline__ float dot2(uint32_t a, uint32_t b, float c) {
    return __builtin_amdgcn_fdot2(__builtin_bit_cast(h2, a),
                                  __builtin_bit_cast(h2, b), c, false);
}
#else
__device__ __forceinline__ float dot2(uint32_t a, uint32_t b, float c) {
    h2 ha = __builtin_bit_cast(h2, a), hb = __builtin_bit_cast(h2, b);
    return c + (float)ha[0]*(float)hb[0] + (float)ha[1]*(float)hb[1];
}
#endif

// tanh(z) = 1 - 2/(exp(2z)+1); v_exp_f32 + v_rcp path.
__device__ __forceinline__ float fast_tanh(float z) {
    float e = __expf(2.0f * z);
    return 1.0f - 2.0f * __builtin_amdgcn_rcpf(e + 1.0f);
}

#define TT 4096
#define NB 32
#define HD 512
#define JL 12              // k-pairs per col in LDS (= 3 state quads; 98 KB total)
#define JTOT 64            // k-pairs per col total (128 k rows / 2)
#define JR (JTOT - JL)     // k-pairs per col in registers (52 -> 208 reg words)

// One block per batch row. 512 threads: kg = tid>>7 (k-slice of 128 state
// rows), colg = tid&127 (4 output columns). W_int resident as fp16 half2
// k-pairs: 12 pairs/col in LDS (ds_read_b128, conflict-free), 52 pairs/col
// in registers. State distribution: LDS-broadcast b128 quads (round 3 showed
// readlane serialization loses to broadcast reads).
//
// __launch_bounds__(512, 1): min 1 wave/EU -> per-wave register budget 512,
// arch-VGPR cap 256. Rounds 1-4 showed the allocator halves the unified file
// (waves_per_eu(2,2) -> 128 VGPR + 128 AGPR; (4,4) -> 64+64 with scratch
// spill). At 256 arch VGPRs, wreg (208 words) + working set (~40) fits in
// true VGPRs -> no v_accvgpr_read per W use per step (~1100 cyc/SIMD/step
// of measured VALU excess in round 2). Runtime occupancy is 1 block/CU
// regardless (32 blocks), so no occupancy loss.
__global__ __launch_bounds__(512, 1)
void esn_kernel(const float* __restrict__ X, const float* __restrict__ W_in,
                const float* __restrict__ W_int, const float* __restrict__ noise,
                float* __restrict__ out)
{
    __shared__ __align__(16) _Float16 s_buf[2][HD];  // 2 KB (state fp16, dbuf)
    __shared__ float pads[4][HD];                    // 8 KB (per-kg partials)
    __shared__ u4 wstash[8 * JL * 64];               // 98 KB [wave][j][lane]

    const int tid  = threadIdx.x;
    const int b    = blockIdx.x;
    const int w    = tid >> 6;      // wave 0..7
    const int l    = tid & 63;      // lane 0..63
    const int kg   = tid >> 7;      // 0..3  (k-slice of 128 state rows)
    const int colg = tid & 127;     // 0..127
    const int c0   = colg * 4;      // first of this thread's 4 columns

    // Input weights for the reduce phase (col = tid).
    const float win0 = W_in[tid*3 + 0];
    const float win1 = W_in[tid*3 + 1];
    const float win2 = W_in[tid*3 + 2];

    // ---- Prologue: load + pack W_int (fp32 -> half2 k-pairs) ----
    uint32_t wreg[4][JR];
    {
        const f4* Wv = (const f4*)W_int;   // W_int[k][h], 4 cols at a time
        for (int j = 0; j < JL; ++j) {     // LDS part: k-pairs 0..JL-1
            const int k = kg*128 + 2*j;
            f4 r0 = Wv[(size_t)k*128 + colg];
            f4 r1 = Wv[(size_t)(k+1)*128 + colg];
            u4 q;
            #pragma unroll
            for (int c = 0; c < 4; ++c) {
                h2 hw; hw[0] = (_Float16)r0[c]; hw[1] = (_Float16)r1[c];
                q[c] = __builtin_bit_cast(uint32_t, hw);
            }
            wstash[(w*JL + j)*64 + l] = q;
        }
        #pragma unroll                      // register part (fully unrolled)
        for (int j = 0; j < JR; ++j) {
            const int k = kg*128 + 2*(JL + j);
            f4 r0 = Wv[(size_t)k*128 + colg];
            f4 r1 = Wv[(size_t)(k+1)*128 + colg];
            #pragma unroll
            for (int c = 0; c < 4; ++c) {
                h2 hw; hw[0] = (_Float16)r0[c]; hw[1] = (_Float16)r1[c];
                wreg[c][j] = __builtin_bit_cast(uint32_t, hw);
            }
        }
    }
    s_buf[0][tid] = (_Float16)0.01f;   // prev0 = 0.01
    __syncthreads();

    const float* Xb   = X   + (size_t)b * TT * 3;
    float*       outb = out + (size_t)b * TT * HD;
    const size_t nb   = (size_t)b * HD + tid;

    int cur = 0;
    for (int t = 0; t < TT; ++t) {
        // Prefetch this step's noise + raw input early; consumed in phase B.
        const float nz = noise[(size_t)t*(NB*HD) + nb];
        const float x0 = Xb[t*3 + 0];
        const float x1 = Xb[t*3 + 1];
        const float x2 = Xb[t*3 + 2];

        // ---- Phase A: partial dot-products over this thread's k-slice ----
        // State as b128 broadcast quads (wave-uniform address), on demand.
        const u4* sv4 = (const u4*)((const uint32_t*)(&s_buf[cur][0]) + kg*64);
        float a0 = 0.f, a1 = 0.f, a2 = 0.f, a3 = 0.f;
        u4 sq;

        // LDS-resident W: 12 x ds_read_b128, conflict-free contiguous layout.
        #pragma unroll
        for (int j = 0; j < JL; ++j) {
            if ((j & 3) == 0) sq = sv4[j >> 2];
            const uint32_t sv = sq[j & 3];
            u4 q = wstash[(w*JL + j)*64 + l];
            a0 = dot2(sv, q[0], a0);
            a1 = dot2(sv, q[1], a1);
            a2 = dot2(sv, q[2], a2);
            a3 = dot2(sv, q[3], a3);
        }
        // Register-resident W: pure VALU.
        #pragma unroll
        for (int j = 0; j < JR; ++j) {
            const int jg = JL + j;               // 12..63, starts quad-aligned
            if ((jg & 3) == 0) sq = sv4[jg >> 2];
            const uint32_t sv = sq[jg & 3];
            a0 = dot2(sv, wreg[0][j], a0);
            a1 = dot2(sv, wreg[1][j], a1);
            a2 = dot2(sv, wreg[2][j], a2);
            a3 = dot2(sv, wreg[3][j], a3);
        }
        f4 pv; pv[0] = a0; pv[1] = a1; pv[2] = a2; pv[3] = a3;
        *(f4*)&pads[kg][c0] = pv;        // 16B aligned, conflict-free
        __syncthreads();

        // ---- Phase B: reduce 4 k-slices, add input+noise, tanh, emit ----
        float z = pads[0][tid] + pads[1][tid] + pads[2][tid] + pads[3][tid];
        z += win0*x0 + win1*x1 + win2*x2 + 0.01f*nz;
        const float s = fast_tanh(z);
        outb[(size_t)t*HD + tid] = s;
        s_buf[cur^1][tid] = (_Float16)s;
        __syncthreads();
        cur ^= 1;
    }
}

extern "C" void kernel_launch(void* const* d_in, const int* in_sizes, int n_in,
                              void* d_out, int out_size, void* d_ws, size_t ws_size,
                              hipStream_t stream)
{
    const float* X     = (const float*)d_in[0];
    const float* W_in  = (const float*)d_in[1];
    const float* W_int = (const float*)d_in[2];
    const float* noise = (const float*)d_in[3];
    float* out = (float*)d_out;

    esn_kernel<<<dim3(NB), dim3(512), 0, stream>>>(X, W_in, W_int, noise, out);
}